// Round 5
// baseline (142.365 us; speedup 1.0000x reference)
//
#include <hip/hip_runtime.h>

typedef short v8s __attribute__((ext_vector_type(8)));
typedef float v4f __attribute__((ext_vector_type(4)));
typedef float v16f __attribute__((ext_vector_type(16)));

// RNE float -> bf16 (matches float_quantize(exp=8, man=7) for these inputs).
__device__ __forceinline__ unsigned short rne_bf16(float f) {
  unsigned u = __float_as_uint(f);
  return (unsigned short)((u + 0x7fffu + ((u >> 16) & 1u)) >> 16);
}
__device__ __forceinline__ float qbf(float f) {
  return __uint_as_float(((unsigned)rne_bf16(f)) << 16);
}

#define CS 72  // LDS col stride in shorts (144 B): b128-aligned at c*16B offsets

// ---------------------------------------------------------------------------
// prep_w: w[n][c][kh][kw] fp32 -> Wt[pos][n][c] bf16   (pos = kh*3+kw)
// ---------------------------------------------------------------------------
__global__ __launch_bounds__(128) void prep_w(const float* __restrict__ w,
                                              unsigned short* __restrict__ Wt) {
  int t = blockIdx.x * 128 + threadIdx.x;  // n*64 + c
  if (t >= 8192) return;
  const float* src = w + (size_t)t * 9;
#pragma unroll
  for (int pos = 0; pos < 9; ++pos) Wt[pos * 8192 + t] = rne_bf16(src[pos]);
}

// ---------------------------------------------------------------------------
// conv_fused: grid (28 row-pairs, 32 b), 256 thr = 4 waves.
// Block tile: 128 outch x 2 out-rows x 56 w. Wave g: 32 outch x 2 rows x 56.
// Staging: wave wv quantizes+transposes input row (oh0-1+wv) directly from x
// (fp32, coalesced along w) into LDS [4 rows][58 cols][64 c] bf16.
// 4 independent acc chains / wave; W register-double-buffered over 9 pos.
// ---------------------------------------------------------------------------
__global__ __launch_bounds__(256, 4) void conv_fused(
    const float* __restrict__ x, const unsigned short* __restrict__ Wt,
    const float* __restrict__ bias, float* __restrict__ out) {
  __shared__ __align__(16) unsigned short xs[4 * 58 * CS];  // [row][col][c]

  const int oh0 = blockIdx.x * 2, b = blockIdx.y;
  const int tid = threadIdx.x;
  const int g = tid >> 6, lane = tid & 63;  // g = outch-group 0..3
  const int lj = lane & 31, lh = lane >> 5;
  const int ljc = lj < 23 ? lj : 23;  // clamp halo for sp-tile1 dead lanes

  // ---- W fragment prefetch (early, hides L2 latency behind staging) ----
  const int wBase = g * 2048 + lj * 64 + lh * 8;
  v8s wA[4], wB[4];
#define PREFETCH(POS, WBUF)                                   \
  {                                                           \
    const unsigned short* wp = Wt + (POS) * 8192 + wBase;     \
    _Pragma("unroll") for (int kk = 0; kk < 4; ++kk)          \
        WBUF[kk] = *(const v8s*)(wp + kk * 16);               \
  }
  PREFETCH(0, wA);
  PREFETCH(1, wB);

  // ---- fused staging: wave g stages row idx g (input row ih = oh0-1+g) ----
  {
    const int ih = oh0 - 1 + g;           // -1 .. 56
    const int w = lane - 1;               // col = lane, w = col-1
    const bool rowok = (ih >= 0) & (ih < 56);
    const bool colok = (lane < 58) & (w >= 0) & (w < 56);
    const float* xr = x + ((size_t)b * 64) * 3136 + (size_t)ih * 56 + w;
    unsigned short* dst = &xs[(g * 58 + lane) * CS];
    if (lane < 58) {
#pragma unroll 8
      for (int c = 0; c < 64; ++c) {
        unsigned short v = 0;
        if (rowok & colok) v = rne_bf16(xr[(size_t)c * 3136]);
        dst[c] = v;
      }
    }
  }
  __syncthreads();

  v16f acc[2][2];  // [row rr][sp tile]
#pragma unroll
  for (int r = 0; r < 2; ++r)
#pragma unroll
    for (int s = 0; s < 2; ++s)
#pragma unroll
      for (int e = 0; e < 16; ++e) acc[r][s][e] = 0.0f;

#define COMPUTE(POS, WBUF)                                                        \
  {                                                                               \
    const int kh = (POS) / 3, kw = (POS) % 3;                                     \
    const unsigned short* p00 = xs + ((0 + kh) * 58 + kw + lj) * CS + lh * 8;     \
    const unsigned short* p01 = xs + ((0 + kh) * 58 + 32 + kw + ljc) * CS + lh * 8; \
    const unsigned short* p10 = xs + ((1 + kh) * 58 + kw + lj) * CS + lh * 8;     \
    const unsigned short* p11 = xs + ((1 + kh) * 58 + 32 + kw + ljc) * CS + lh * 8; \
    _Pragma("unroll") for (int kk = 0; kk < 4; ++kk) {                            \
      v8s f00 = *(const v8s*)(p00 + kk * 16);                                     \
      v8s f01 = *(const v8s*)(p01 + kk * 16);                                     \
      v8s f10 = *(const v8s*)(p10 + kk * 16);                                     \
      v8s f11 = *(const v8s*)(p11 + kk * 16);                                     \
      acc[0][0] = __builtin_amdgcn_mfma_f32_32x32x16_bf16(WBUF[kk], f00, acc[0][0], 0, 0, 0); \
      acc[0][1] = __builtin_amdgcn_mfma_f32_32x32x16_bf16(WBUF[kk], f01, acc[0][1], 0, 0, 0); \
      acc[1][0] = __builtin_amdgcn_mfma_f32_32x32x16_bf16(WBUF[kk], f10, acc[1][0], 0, 0, 0); \
      acc[1][1] = __builtin_amdgcn_mfma_f32_32x32x16_bf16(WBUF[kk], f11, acc[1][1], 0, 0, 0); \
    }                                                                             \
  }

  COMPUTE(0, wA); PREFETCH(2, wA);
  COMPUTE(1, wB); PREFETCH(3, wB);
  COMPUTE(2, wA); PREFETCH(4, wA);
  COMPUTE(3, wB); PREFETCH(5, wB);
  COMPUTE(4, wA); PREFETCH(6, wA);
  COMPUTE(5, wB); PREFETCH(7, wB);
  COMPUTE(6, wA); PREFETCH(8, wA);
  COMPUTE(7, wB);
  COMPUTE(8, wA);

  // ---- epilogue: quantized bias + store (C/D layout verified R1-R4) ----
  const int chb = g * 32;
  v4f qb[4];
#pragma unroll
  for (int gg = 0; gg < 4; ++gg) {
    v4f t = *(const v4f*)(bias + chb + gg * 8 + lh * 4);
    qb[gg][0] = qbf(t[0]); qb[gg][1] = qbf(t[1]);
    qb[gg][2] = qbf(t[2]); qb[gg][3] = qbf(t[3]);
  }

#pragma unroll
  for (int rr = 0; rr < 2; ++rr) {
    float* ob = out + (size_t)b * 128 * 3136 + (oh0 + rr) * 56;
#pragma unroll
    for (int e = 0; e < 16; ++e) {
      int ch = chb + (e & 3) + 8 * (e >> 2) + 4 * lh;
      float bv = qb[e >> 2][e & 3];
      float* pr = ob + (size_t)ch * 3136;
      pr[lj] = acc[rr][0][e] + bv;                    // ow 0..31
      if (lj < 24) pr[32 + lj] = acc[rr][1][e] + bv;  // ow 32..55
    }
  }
}

extern "C" void kernel_launch(void* const* d_in, const int* in_sizes, int n_in,
                              void* d_out, int out_size, void* d_ws, size_t ws_size,
                              hipStream_t stream) {
  const float* x = (const float*)d_in[0];     // [32,64,56,56]
  const float* w = (const float*)d_in[1];     // [128,64,3,3]
  const float* bias = (const float*)d_in[2];  // [128]
  float* out = (float*)d_out;                 // [32,128,56,56] fp32

  unsigned short* Wt = (unsigned short*)d_ws;  // 9*128*64 bf16 = 147 KB

  prep_w<<<64, 128, 0, stream>>>(w, Wt);
  conv_fused<<<dim3(28, 32), 256, 0, stream>>>(x, Wt, bias, out);
}

// Round 6
// 115.052 us; speedup vs baseline: 1.2374x; 1.2374x over previous
//
#include <hip/hip_runtime.h>

typedef short v8s __attribute__((ext_vector_type(8)));
typedef float v4f __attribute__((ext_vector_type(4)));
typedef float v16f __attribute__((ext_vector_type(16)));

// RNE float -> bf16 (matches float_quantize(exp=8, man=7) for these inputs).
__device__ __forceinline__ unsigned short rne_bf16(float f) {
  unsigned u = __float_as_uint(f);
  return (unsigned short)((u + 0x7fffu + ((u >> 16) & 1u)) >> 16);
}
__device__ __forceinline__ float qbf(float f) {
  return __uint_as_float(((unsigned)rne_bf16(f)) << 16);
}

#define CS 72  // LDS col stride (shorts): 144 B; conflict-benign, b128-aligned

// ---------------------------------------------------------------------------
// prep: blocks 0..1791 quantize+transpose x -> Xp[b][h+1][w+1][c] (58x58 NHWC
// bf16, borders zeroed). Blocks 1792..1823: weights -> fragment-major Wt2:
//   Wt2[((pos*4 + kk)*4 + n>>5)*512 + lane*8 + (c&7)],
//   lane = (n&31) + 32*((c>>3)&1), kk = c>>4
// so conv's W loads are single fully-coalesced 1024-B v8s instructions.
// ---------------------------------------------------------------------------
__global__ __launch_bounds__(256) void prep(const float* __restrict__ x,
                                            const float* __restrict__ w,
                                            unsigned short* __restrict__ Xp,
                                            unsigned short* __restrict__ Wt2) {
  const int blk = blockIdx.x;
  const int tid = threadIdx.x;

  if (blk >= 1792) {  // ---- weight reorder ----
    int t = (blk - 1792) * 256 + tid;  // 0..8191 = n*64 + c
    int n = t >> 6, c = t & 63;
    int kk = c >> 4;
    int lane = (n & 31) + 32 * ((c >> 3) & 1);
    const float* src = w + (size_t)t * 9;
#pragma unroll
    for (int pos = 0; pos < 9; ++pos) {
      int idx = (((pos * 4 + kk) * 4 + (n >> 5)) << 9) + lane * 8 + (c & 7);
      Wt2[idx] = rne_bf16(src[pos]);
    }
    return;
  }

  const int b = blk / 56, h = blk % 56;
  __shared__ __align__(16) unsigned short tile[56 * CS];  // [w][c]

  // zero pad borders (ws is re-poisoned before every launch)
  unsigned short* rowp = Xp + (((size_t)b * 58 + (h + 1)) * 58) * 64;
  if (tid < 64) { rowp[tid] = 0; rowp[57 * 64 + tid] = 0; }
  if (h == 0) {
    unsigned short* r0 = Xp + ((size_t)b * 58 * 58) * 64;
    unsigned short* r57 = r0 + (size_t)57 * 58 * 64;
    for (int i = tid; i < 58 * 64; i += 256) { r0[i] = 0; r57[i] = 0; }
  }

  // phase 1: 448 slots = 8 chan-octets * 56 w; reads coalesced along w
#pragma unroll
  for (int it = 0; it < 2; ++it) {
    int i = it * 256 + tid;
    if (i < 448) {
      int c8 = i / 56, ww = i - c8 * 56;
      const float* xb = x + ((size_t)(b * 64 + c8 * 8)) * 3136 + h * 56 + ww;
      v8s pk;
#pragma unroll
      for (int j = 0; j < 8; ++j) pk[j] = (short)rne_bf16(xb[(size_t)j * 3136]);
      *(v8s*)&tile[ww * CS + c8 * 8] = pk;
    }
  }
  __syncthreads();

  // phase 2: interior write, 128 B contiguous per w
  unsigned short* dst = Xp + (((size_t)b * 58 + (h + 1)) * 58 + 1) * 64;
#pragma unroll
  for (int it = 0; it < 2; ++it) {
    int i = it * 256 + tid;
    if (i < 448) {
      int ww = i >> 3, cb = i & 7;
      *(v8s*)&dst[ww * 64 + cb * 8] = *(const v8s*)&tile[ww * CS + cb * 8];
    }
  }
}

// ---------------------------------------------------------------------------
// conv: grid (14 row-quads, 2 ch-halves, 32 b) = 896 blocks, 256 thr = 4 waves.
// Block: 64 outch x 4 oh rows x 56 w. Wave w: row oh0+w, 64 outch x 56 sp,
// 4 independent acc chains, 2 MFMA per ds_read (W fragments in registers,
// double-buffered over the 9 positions, coalesced via Wt2 layout).
// Epilogue: LDS transpose (2 phases of 32 ch) -> full-128B-line dwordx4 stores
// (out offset = ch*12544 + quad*896 + j*16 bytes: all 16B-aligned, rows exact
// multiples of 128B lines -> zero partial-line RMW).
// ---------------------------------------------------------------------------
__global__ __launch_bounds__(256, 3) void conv(const unsigned short* __restrict__ Xp,
                                               const unsigned short* __restrict__ Wt2,
                                               const float* __restrict__ bias,
                                               float* __restrict__ out) {
  __shared__ __align__(16) char smem[6 * 58 * CS * 2 + 256];
  unsigned short* xs = (unsigned short*)smem;      // [6 rows][58 cols][64 c]
  float* fbuf = (float*)smem;                      // epilogue union: [32 ch][228]
  float* qb = (float*)(smem + 6 * 58 * CS * 2);    // 64 quantized biases

  const int quad = blockIdx.x, chh = blockIdx.y, b = blockIdx.z;
  const int oh0 = quad * 4;
  const int ch_base = chh * 64;
  const int tid = threadIdx.x;
  const int wv = tid >> 6, lane = tid & 63;
  const int lj = lane & 31, lh = lane >> 5;
  const int lj1 = 28 + (lj < 27 ? lj : 27);  // sp-tile1 col offset (clamped)

  if (tid < 64) qb[tid] = qbf(bias[ch_base + tid]);

  // ---- W fragment prefetch: one coalesced 1024-B v8s load per (kk, ct) ----
  const unsigned short* wt0 = Wt2 + lane * 8;
  v8s wA[8], wB[8];
#define PREFETCH(POS, WBUF)                                                  \
  {                                                                          \
    _Pragma("unroll") for (int kk = 0; kk < 4; ++kk) {                       \
      WBUF[kk]     = *(const v8s*)(wt0 + ((((POS)*4 + kk) * 4 + chh * 2) << 9));     \
      WBUF[4 + kk] = *(const v8s*)(wt0 + ((((POS)*4 + kk) * 4 + chh * 2 + 1) << 9)); \
    }                                                                        \
  }
  PREFETCH(0, wA);
  PREFETCH(1, wB);

  // ---- stage 6 padded rows (oh0..oh0+5) x 58 cols x 64 c, linear source ----
  const unsigned short* xpb = Xp + (((size_t)b * 58 + oh0) * 58) * 64;
#pragma unroll
  for (int it = 0; it < 11; ++it) {
    int i = it * 256 + tid;
    if (i < 2784) *(v8s*)&xs[(i >> 3) * CS + (i & 7) * 8] = *(const v8s*)&xpb[(size_t)i * 8];
  }
  __syncthreads();

  v16f acc[2][2];  // [ct][sp tile]
#pragma unroll
  for (int a = 0; a < 2; ++a)
#pragma unroll
    for (int s = 0; s < 2; ++s)
#pragma unroll
      for (int e = 0; e < 16; ++e) acc[a][s][e] = 0.0f;

#define COMPUTE(POS, WBUF)                                                     \
  {                                                                            \
    const int kh = (POS) / 3, kw = (POS) % 3;                                  \
    const unsigned short* p0 = xs + ((wv + kh) * 58 + kw + lj) * CS + lh * 8;  \
    const unsigned short* p1 = xs + ((wv + kh) * 58 + kw + lj1) * CS + lh * 8; \
    _Pragma("unroll") for (int kk = 0; kk < 4; ++kk) {                         \
      v8s f0 = *(const v8s*)(p0 + kk * 16);                                    \
      v8s f1 = *(const v8s*)(p1 + kk * 16);                                    \
      acc[0][0] = __builtin_amdgcn_mfma_f32_32x32x16_bf16(WBUF[kk], f0, acc[0][0], 0, 0, 0); \
      acc[0][1] = __builtin_amdgcn_mfma_f32_32x32x16_bf16(WBUF[kk], f1, acc[0][1], 0, 0, 0); \
      acc[1][0] = __builtin_amdgcn_mfma_f32_32x32x16_bf16(WBUF[4 + kk], f0, acc[1][0], 0, 0, 0); \
      acc[1][1] = __builtin_amdgcn_mfma_f32_32x32x16_bf16(WBUF[4 + kk], f1, acc[1][1], 0, 0, 0); \
    }                                                                          \
  }

  COMPUTE(0, wA); PREFETCH(2, wA);
  COMPUTE(1, wB); PREFETCH(3, wB);
  COMPUTE(2, wA); PREFETCH(4, wA);
  COMPUTE(3, wB); PREFETCH(5, wB);
  COMPUTE(4, wA); PREFETCH(6, wA);
  COMPUTE(5, wB); PREFETCH(7, wB);
  COMPUTE(6, wA); PREFETCH(8, wA);
  COMPUTE(7, wB);
  COMPUTE(8, wA);

  // ---- epilogue: LDS transpose -> full-line vectorized stores ----
  __syncthreads();  // all xs reads done; fbuf may now alias xs
#pragma unroll
  for (int ct = 0; ct < 2; ++ct) {
    if (lj < 28) {
#pragma unroll
      for (int e = 0; e < 16; ++e) {
        int chl = (e & 3) + 8 * (e >> 2) + 4 * lh;  // 0..31 (C/D layout, verified)
        fbuf[chl * 228 + wv * 56 + lj] = acc[ct][0][e];
        fbuf[chl * 228 + wv * 56 + 28 + lj] = acc[ct][1][e];
      }
    }
    __syncthreads();
#pragma unroll
    for (int p = 0; p < 8; ++p) {
      int i = p * 256 + tid;
      int chl = i >> 6, j = i & 63;
      if (j < 56) {
        v4f v = *(const v4f*)&fbuf[chl * 228 + j * 4];
        float bb = qb[ct * 32 + chl];
        v[0] += bb; v[1] += bb; v[2] += bb; v[3] += bb;
        float* dst = out + (size_t)(b * 128 + ch_base + ct * 32 + chl) * 3136 + quad * 224 + j * 4;
        *(v4f*)dst = v;
      }
    }
    if (ct == 0) __syncthreads();  // readers done before phase-1 overwrites fbuf
  }
}

extern "C" void kernel_launch(void* const* d_in, const int* in_sizes, int n_in,
                              void* d_out, int out_size, void* d_ws, size_t ws_size,
                              hipStream_t stream) {
  const float* x = (const float*)d_in[0];     // [32,64,56,56]
  const float* w = (const float*)d_in[1];     // [128,64,3,3]
  const float* bias = (const float*)d_in[2];  // [128]
  float* out = (float*)d_out;                 // [32,128,56,56] fp32

  unsigned short* Xp = (unsigned short*)d_ws;              // 32*58*58*64 bf16
  const size_t XP_BYTES = (size_t)32 * 58 * 58 * 64 * 2;   // 13,778,944 B
  unsigned short* Wt2 = (unsigned short*)((char*)d_ws + XP_BYTES);  // 147 KB

  prep<<<1792 + 32, 256, 0, stream>>>(x, w, Xp, Wt2);
  conv<<<dim3(14, 2, 32), 256, 0, stream>>>(Xp, Wt2, bias, out);
}